// Round 3
// baseline (990.865 us; speedup 1.0000x reference)
//
#include <hip/hip_runtime.h>
#include <hip/hip_bf16.h>

// GCN: 4 layers. N=100000, E=1600000, F=H=128, C=40. fp32.
// R2 changes vs R1:
//  - gemm_f32_128: BK=16, double-buffered LDS (1 sync/iter), register prefetch
//  - scatter_edges packs (src, dinv[src]) into int2 srcW -> agg reads are
//    sequential, random dinv gather removed from agg dependency chain
//  - agg_kernel: 8-way unrolled, 8 independent accumulators

#define N_NODES 100000
#define N_EDGES 1600000

// ---------------- CSR build ----------------

__global__ void init_counts(int* counts, int* cursor, int n) {
    int i = blockIdx.x * blockDim.x + threadIdx.x;
    if (i < n) { counts[i] = 1; cursor[i] = 0; }
}

__global__ void count_edges(const int* __restrict__ dst, int* __restrict__ counts, int e) {
    int i = blockIdx.x * blockDim.x + threadIdx.x;
    if (i < e) atomicAdd(&counts[dst[i]], 1);
}

__global__ void compute_dinv(const int* __restrict__ counts, float* __restrict__ dinv, int n) {
    int i = blockIdx.x * blockDim.x + threadIdx.x;
    if (i < n) dinv[i] = 1.0f / sqrtf((float)counts[i]);
}

__global__ __launch_bounds__(256) void scan_phase1(const int* __restrict__ counts,
                                                   int* __restrict__ blockSums, int n) {
    __shared__ int red[256];
    int t = threadIdx.x;
    int base = blockIdx.x * 1024 + t * 4;
    int s = 0;
    if (base + 3 < n) {
        int4 v = *(const int4*)(counts + base);
        s = v.x + v.y + v.z + v.w - 4;
    } else {
        for (int j = 0; j < 4; j++) if (base + j < n) s += counts[base + j] - 1;
    }
    red[t] = s;
    __syncthreads();
    for (int off = 128; off > 0; off >>= 1) {
        if (t < off) red[t] += red[t + off];
        __syncthreads();
    }
    if (t == 0) blockSums[blockIdx.x] = red[0];
}

__global__ __launch_bounds__(1024) void scan_phase2(int* __restrict__ blockSums, int nb) {
    __shared__ int sh[1024];
    int t = threadIdx.x;
    sh[t] = (t < nb) ? blockSums[t] : 0;
    __syncthreads();
    for (int off = 1; off < 1024; off <<= 1) {
        int v = (t >= off) ? sh[t - off] : 0;
        __syncthreads();
        sh[t] += v;
        __syncthreads();
    }
    if (t < nb) blockSums[t] = (t == 0) ? 0 : sh[t - 1];
}

__global__ __launch_bounds__(256) void scan_phase3(const int* __restrict__ counts,
                                                   const int* __restrict__ blockSums,
                                                   int* __restrict__ offsets, int n, int total) {
    __shared__ int red[256];
    int t = threadIdx.x;
    int base = blockIdx.x * 1024 + t * 4;
    int c[4];
#pragma unroll
    for (int j = 0; j < 4; j++) c[j] = (base + j < n) ? counts[base + j] - 1 : 0;
    int s = c[0] + c[1] + c[2] + c[3];
    red[t] = s;
    __syncthreads();
    for (int off = 1; off < 256; off <<= 1) {
        int v = (t >= off) ? red[t - off] : 0;
        __syncthreads();
        red[t] += v;
        __syncthreads();
    }
    int prefix = blockSums[blockIdx.x] + ((t == 0) ? 0 : red[t - 1]);
#pragma unroll
    for (int j = 0; j < 4; j++) {
        if (base + j < n) offsets[base + j] = prefix;
        prefix += c[j];
    }
    if (blockIdx.x == 0 && t == 0) offsets[n] = total;
}

// pack (src, dinv[src]) so agg's inner loop is fully sequential
__global__ void scatter_edges(const int* __restrict__ src, const int* __restrict__ dst,
                              const int* __restrict__ offsets, int* __restrict__ cursor,
                              const float* __restrict__ dinv,
                              int2* __restrict__ srcW, int e) {
    int i = blockIdx.x * blockDim.x + threadIdx.x;
    if (i < e) {
        int d = dst[i];
        int s = src[i];
        int pos = offsets[d] + atomicAdd(&cursor[d], 1);
        srcW[pos] = make_int2(s, __float_as_int(dinv[s]));
    }
}

// ---------------- GEMM: [M,128] @ [128,128] -> [M,128], fp32 vector ----------------
// BM=128, BN=128, BK=16, 256 threads, 8x8 microtile, double-buffered LDS.

__global__ __launch_bounds__(256) void gemm_f32_128(const float* __restrict__ A,
                                                    const float* __restrict__ B,
                                                    float* __restrict__ C, int M) {
    __shared__ float As[2][16][132];   // [k][m], padded
    __shared__ float Bs[2][16][128];   // [k][n]
    int t = threadIdx.x;
    int block_row = blockIdx.x * 128;

    // staging: A -> thread loads 8 consecutive k of one row
    int aRow = t >> 1;          // 0..127
    int aK   = (t & 1) * 8;     // 0 or 8
    // B -> thread loads 8 consecutive n of one k-row
    int bK   = t >> 4;          // 0..15
    int bCol = (t & 15) * 8;    // 0..120
    // microtile
    int tr = (t >> 4) * 8;      // 0..120
    int tc = (t & 15) * 8;      // 0..120

    int gRowA = block_row + aRow; if (gRowA >= M) gRowA = M - 1;  // clamp; store guarded
    const float* Aptr = A + (size_t)gRowA * 128 + aK;
    const float* Bptr = B + (size_t)bK * 128 + bCol;

    float acc[8][8];
#pragma unroll
    for (int i = 0; i < 8; i++)
#pragma unroll
        for (int j = 0; j < 8; j++) acc[i][j] = 0.0f;

    // prefetch tile 0
    float4 pa0 = *(const float4*)(Aptr + 0);
    float4 pa1 = *(const float4*)(Aptr + 4);
    float4 pb0 = *(const float4*)(Bptr + 0);
    float4 pb1 = *(const float4*)(Bptr + 4);

    for (int iter = 0; iter < 8; ++iter) {
        int buf = iter & 1;
        // stage prefetched regs into LDS
        As[buf][aK + 0][aRow] = pa0.x;
        As[buf][aK + 1][aRow] = pa0.y;
        As[buf][aK + 2][aRow] = pa0.z;
        As[buf][aK + 3][aRow] = pa0.w;
        As[buf][aK + 4][aRow] = pa1.x;
        As[buf][aK + 5][aRow] = pa1.y;
        As[buf][aK + 6][aRow] = pa1.z;
        As[buf][aK + 7][aRow] = pa1.w;
        *(float4*)&Bs[buf][bK][bCol]     = pb0;
        *(float4*)&Bs[buf][bK][bCol + 4] = pb1;
        __syncthreads();
        // issue next tile's global loads (consumed next iter; overlaps compute)
        if (iter < 7) {
            int k0 = (iter + 1) * 16;
            pa0 = *(const float4*)(Aptr + k0);
            pa1 = *(const float4*)(Aptr + k0 + 4);
            pb0 = *(const float4*)(Bptr + (size_t)k0 * 128);
            pb1 = *(const float4*)(Bptr + (size_t)k0 * 128 + 4);
        }
#pragma unroll
        for (int k = 0; k < 16; ++k) {
            float am[8], bn[8];
            *(float4*)&am[0] = *(const float4*)&As[buf][k][tr];
            *(float4*)&am[4] = *(const float4*)&As[buf][k][tr + 4];
            *(float4*)&bn[0] = *(const float4*)&Bs[buf][k][tc];
            *(float4*)&bn[4] = *(const float4*)&Bs[buf][k][tc + 4];
#pragma unroll
            for (int i = 0; i < 8; i++)
#pragma unroll
                for (int j = 0; j < 8; j++) acc[i][j] += am[i] * bn[j];
        }
    }

#pragma unroll
    for (int i = 0; i < 8; i++) {
        int gr = block_row + tr + i;
        if (gr < M) {
#pragma unroll
            for (int j = 0; j < 8; j += 4) {
                float4 v = make_float4(acc[i][j], acc[i][j+1], acc[i][j+2], acc[i][j+3]);
                *(float4*)(C + (size_t)gr * 128 + tc + j) = v;
            }
        }
    }
}

// ---------------- GEMM: [M,128] @ [128,40] -> [M,40] ----------------

__global__ __launch_bounds__(320) void gemm_f32_40(const float* __restrict__ A,
                                                   const float* __restrict__ B,
                                                   float* __restrict__ C, int M) {
    __shared__ float Ws[128][40];
    __shared__ float Xs[32][132];
    int t = threadIdx.x;
    int block_row = blockIdx.x * 32;

    for (int i = t; i < 128 * 40; i += 320) ((float*)Ws)[i] = B[i];
    for (int idx = t; idx < 1024; idx += 320) {
        int row = idx >> 5;
        int k4  = (idx & 31) << 2;
        int gr = block_row + row; if (gr >= M) gr = M - 1;
        float4 v = *(const float4*)(A + (size_t)gr * 128 + k4);
        *(float4*)&Xs[row][k4] = v;
    }
    __syncthreads();

    int r  = t / 10;
    int c0 = (t % 10) * 4;
    float4 acc = make_float4(0.f, 0.f, 0.f, 0.f);
    for (int k = 0; k < 128; k += 4) {
        float4 xv = *(const float4*)&Xs[r][k];
#pragma unroll
        for (int j = 0; j < 4; j++) {
            float xj = (j == 0) ? xv.x : (j == 1) ? xv.y : (j == 2) ? xv.z : xv.w;
            float4 wv = *(const float4*)&Ws[k + j][c0];
            acc.x += xj * wv.x; acc.y += xj * wv.y;
            acc.z += xj * wv.z; acc.w += xj * wv.w;
        }
    }
    int gr = block_row + r;
    if (gr < M) *(float4*)(C + (size_t)gr * 40 + c0) = acc;
}

// ---------------- CSR aggregation: one wave per node, 8-way unrolled ----------------
// out[i] = relu?( dinv[i] * (dinv[i]*h[i] + sum_s w_s*h[s]) + b ),  w_s = dinv[s]

template <int NF, bool RELU>
__global__ __launch_bounds__(256) void agg_kernel(const float* __restrict__ h,
                                                  const float* __restrict__ dinv,
                                                  const int* __restrict__ offsets,
                                                  const int2* __restrict__ srcW,
                                                  const float* __restrict__ bias,
                                                  float* __restrict__ out, int n) {
    int wave = threadIdx.x >> 6;
    int lane = threadIdx.x & 63;
    int node = blockIdx.x * 4 + wave;
    if (node >= n) return;

    int f = lane * 2;
    bool act = (f < NF);
    float di = dinv[node];

    float2 a0 = make_float2(0.f, 0.f), a1 = a0, a2 = a0, a3 = a0;
    float2 a4 = a0, a5 = a0, a6 = a0, a7 = a0;
    if (act) {
        float2 hv = *(const float2*)(h + (size_t)node * NF + f);
        a0.x = di * hv.x; a0.y = di * hv.y;
    }

    int beg = offsets[node], end = offsets[node + 1];
    int idx = beg;
    for (; idx + 8 <= end; idx += 8) {
        int2 e0 = srcW[idx];     int2 e1 = srcW[idx + 1];
        int2 e2 = srcW[idx + 2]; int2 e3 = srcW[idx + 3];
        int2 e4 = srcW[idx + 4]; int2 e5 = srcW[idx + 5];
        int2 e6 = srcW[idx + 6]; int2 e7 = srcW[idx + 7];
        if (act) {
            float2 h0 = *(const float2*)(h + (size_t)e0.x * NF + f);
            float2 h1 = *(const float2*)(h + (size_t)e1.x * NF + f);
            float2 h2 = *(const float2*)(h + (size_t)e2.x * NF + f);
            float2 h3 = *(const float2*)(h + (size_t)e3.x * NF + f);
            float2 h4 = *(const float2*)(h + (size_t)e4.x * NF + f);
            float2 h5 = *(const float2*)(h + (size_t)e5.x * NF + f);
            float2 h6 = *(const float2*)(h + (size_t)e6.x * NF + f);
            float2 h7 = *(const float2*)(h + (size_t)e7.x * NF + f);
            float w0 = __int_as_float(e0.y), w1 = __int_as_float(e1.y);
            float w2 = __int_as_float(e2.y), w3 = __int_as_float(e3.y);
            float w4 = __int_as_float(e4.y), w5 = __int_as_float(e5.y);
            float w6 = __int_as_float(e6.y), w7 = __int_as_float(e7.y);
            a0.x += w0 * h0.x; a0.y += w0 * h0.y;
            a1.x += w1 * h1.x; a1.y += w1 * h1.y;
            a2.x += w2 * h2.x; a2.y += w2 * h2.y;
            a3.x += w3 * h3.x; a3.y += w3 * h3.y;
            a4.x += w4 * h4.x; a4.y += w4 * h4.y;
            a5.x += w5 * h5.x; a5.y += w5 * h5.y;
            a6.x += w6 * h6.x; a6.y += w6 * h6.y;
            a7.x += w7 * h7.x; a7.y += w7 * h7.y;
        }
    }
    for (; idx + 2 <= end; idx += 2) {
        int2 e0 = srcW[idx]; int2 e1 = srcW[idx + 1];
        if (act) {
            float2 h0 = *(const float2*)(h + (size_t)e0.x * NF + f);
            float2 h1 = *(const float2*)(h + (size_t)e1.x * NF + f);
            float w0 = __int_as_float(e0.y), w1 = __int_as_float(e1.y);
            a0.x += w0 * h0.x; a0.y += w0 * h0.y;
            a1.x += w1 * h1.x; a1.y += w1 * h1.y;
        }
    }
    if (idx < end) {
        int2 e0 = srcW[idx];
        if (act) {
            float2 h0 = *(const float2*)(h + (size_t)e0.x * NF + f);
            float w0 = __int_as_float(e0.y);
            a2.x += w0 * h0.x; a2.y += w0 * h0.y;
        }
    }

    if (act) {
        float2 o;
        o.x = di * (((a0.x + a1.x) + (a2.x + a3.x)) + ((a4.x + a5.x) + (a6.x + a7.x))) + bias[f];
        o.y = di * (((a0.y + a1.y) + (a2.y + a3.y)) + ((a4.y + a5.y) + (a6.y + a7.y))) + bias[f + 1];
        if (RELU) { o.x = fmaxf(o.x, 0.f); o.y = fmaxf(o.y, 0.f); }
        *(float2*)(out + (size_t)node * NF + f) = o;
    }
}

// ---------------- orchestration ----------------

extern "C" void kernel_launch(void* const* d_in, const int* in_sizes, int n_in,
                              void* d_out, int out_size, void* d_ws, size_t ws_size,
                              hipStream_t stream) {
    const float* x  = (const float*)d_in[0];
    const int* edge = (const int*)d_in[1];
    const float* W1 = (const float*)d_in[2]; const float* b1 = (const float*)d_in[3];
    const float* W2 = (const float*)d_in[4]; const float* b2 = (const float*)d_in[5];
    const float* W3 = (const float*)d_in[6]; const float* b3 = (const float*)d_in[7];
    const float* W4 = (const float*)d_in[8]; const float* b4 = (const float*)d_in[9];

    const int N = in_sizes[0] / 128;      // 100000
    const int E = in_sizes[1] / 2;        // 1600000
    const int* src = edge;
    const int* dst = edge + E;

    float* out_final = (float*)d_out;                    // [N,40]
    float* x_latent  = (float*)d_out + (size_t)N * 40;   // [N,128]

    // workspace carve-up
    char* w = (char*)d_ws;
    int* counts    = (int*)w;  w += (size_t)N * 4;
    int* cursor    = (int*)w;  w += (size_t)N * 4;
    int* offsets   = (int*)w;  w += (size_t)(N + 4) * 4;
    float* dinv    = (float*)w; w += (size_t)N * 4;
    int* blockSums = (int*)w;  w += (size_t)1024 * 4;
    w = (char*)(((uintptr_t)w + 255) & ~(uintptr_t)255);
    int2* srcW     = (int2*)w; w += (size_t)E * 8;
    float* hA = (float*)w; w += (size_t)N * 128 * 4;
    float* hB = (float*)w; w += (size_t)N * 128 * 4;

    int gN = (N + 255) / 256;
    int gE = (E + 255) / 256;
    int nb = (N + 1023) / 1024;   // 98

    init_counts<<<gN, 256, 0, stream>>>(counts, cursor, N);
    count_edges<<<gE, 256, 0, stream>>>(dst, counts, E);
    compute_dinv<<<gN, 256, 0, stream>>>(counts, dinv, N);
    scan_phase1<<<nb, 256, 0, stream>>>(counts, blockSums, N);
    scan_phase2<<<1, 1024, 0, stream>>>(blockSums, nb);
    scan_phase3<<<nb, 256, 0, stream>>>(counts, blockSums, offsets, N, E);
    scatter_edges<<<gE, 256, 0, stream>>>(src, dst, offsets, cursor, dinv, srcW, E);

    int gGemm = (N + 127) / 128;   // 782
    int gAgg  = (N + 3) / 4;       // 25000

    gemm_f32_128<<<gGemm, 256, 0, stream>>>(x, W1, hA, N);
    agg_kernel<128, true><<<gAgg, 256, 0, stream>>>(hA, dinv, offsets, srcW, b1, hB, N);
    gemm_f32_128<<<gGemm, 256, 0, stream>>>(hB, W2, hA, N);
    agg_kernel<128, true><<<gAgg, 256, 0, stream>>>(hA, dinv, offsets, srcW, b2, hB, N);
    gemm_f32_128<<<gGemm, 256, 0, stream>>>(hB, W3, hA, N);
    agg_kernel<128, true><<<gAgg, 256, 0, stream>>>(hA, dinv, offsets, srcW, b3, x_latent, N);
    gemm_f32_40<<<(N + 31) / 32, 320, 0, stream>>>(x_latent, W4, hA, N);
    agg_kernel<40, false><<<gAgg, 256, 0, stream>>>(hA, dinv, offsets, srcW, b4, out_final, N);
}